// Round 7
// baseline (442.512 us; speedup 1.0000x reference)
//
#include <hip/hip_runtime.h>
#include <hip/hip_bf16.h>

// Problem constants
#define BB 256          // batch
#define FF 128          // features
#define CC 100          // classes
#define KG 512          // split-K groups (k-blocks of main_gemm)
#define ITPB 16         // it-pairs per main_gemm block (KG*ITPB = 8192)

typedef short bf16x8 __attribute__((ext_vector_type(8)));
typedef float f32x4 __attribute__((ext_vector_type(4)));
typedef _Float16 f16x8 __attribute__((ext_vector_type(8)));

static __device__ inline unsigned short f2bf(float f) {
    unsigned u = __float_as_uint(f);
    u += 0x7fffu + ((u >> 16) & 1u);   // RNE
    return (unsigned short)(u >> 16);
}
static __device__ inline float bf2f(unsigned short h) {
    return __uint_as_float(((unsigned)h) << 16);
}
// packed f32x2 -> bf16x2 (RNE), low16 = a
static __device__ inline unsigned pk2(float a, float b) {
    __hip_bfloat162 h = __float22bfloat162_rn(float2{a, b});
    union { __hip_bfloat162 h2; unsigned u; } cv; cv.h2 = h;
    return cv.u;
}

// ---------------------------------------------------------------------------
// Kernel 1: fv[row][b] = sigmoid(x[b,:] . sel_W[row,:] + sel_b[row])  (bf16)
// row = it*6 + d  ->  fv[row*256 + b]
// ---------------------------------------------------------------------------
__global__ __launch_bounds__(256) void fv_kernel(
    const float* __restrict__ x, const float* __restrict__ selW,
    const float* __restrict__ selb, unsigned short* __restrict__ fvout)
{
    __shared__ unsigned short wt[128 * 136];
    __shared__ unsigned short xt[128 * 136];
    __shared__ float sb[128];

    const int tid = threadIdx.x;
    const int m0 = blockIdx.x * 128;
    const int n0 = blockIdx.y * 128;

    #pragma unroll 4
    for (int pass = 0; pass < 16; ++pass) {
        int idx = pass * 256 + tid;
        int r = idx >> 5, f4 = idx & 31;
        float4 v = *((const float4*)(selW + (size_t)(m0 + r) * FF) + f4);
        float4 vx = *((const float4*)(x + (size_t)(n0 + r) * FF) + f4);
        ushort4 h;
        h.x = f2bf(v.x); h.y = f2bf(v.y); h.z = f2bf(v.z); h.w = f2bf(v.w);
        *(ushort4*)(wt + r * 136 + f4 * 4) = h;
        ushort4 hx;
        hx.x = f2bf(vx.x); hx.y = f2bf(vx.y); hx.z = f2bf(vx.z); hx.w = f2bf(vx.w);
        *(ushort4*)(xt + r * 136 + f4 * 4) = hx;
    }
    if (tid < 128) sb[tid] = selb[m0 + tid];
    __syncthreads();

    const int w = tid >> 6, lane = tid & 63;
    const int q = lane >> 4, l15 = lane & 15;
    const int mq = w & 1, nq = w >> 1;

    f32x4 zero4 = {0.f, 0.f, 0.f, 0.f};
    f32x4 acc[4][4];
    #pragma unroll
    for (int i = 0; i < 4; ++i)
        #pragma unroll
        for (int j = 0; j < 4; ++j) acc[i][j] = zero4;

    #pragma unroll
    for (int ch = 0; ch < 4; ++ch) {
        bf16x8 a[4];
        #pragma unroll
        for (int ms = 0; ms < 4; ++ms)
            a[ms] = *(const bf16x8*)(wt + (mq * 64 + ms * 16 + l15) * 136 + ch * 32 + q * 8);
        #pragma unroll
        for (int ns = 0; ns < 4; ++ns) {
            bf16x8 bfr = *(const bf16x8*)(xt + (nq * 64 + ns * 16 + l15) * 136 + ch * 32 + q * 8);
            #pragma unroll
            for (int ms = 0; ms < 4; ++ms)
                acc[ms][ns] = __builtin_amdgcn_mfma_f32_16x16x32_bf16(a[ms], bfr, acc[ms][ns], 0, 0, 0);
        }
    }

    #pragma unroll
    for (int ms = 0; ms < 4; ++ms) {
        int rowl = mq * 64 + ms * 16 + q * 4;
        #pragma unroll
        for (int ns = 0; ns < 4; ++ns) {
            int b = n0 + nq * 64 + ns * 16 + l15;
            #pragma unroll
            for (int reg = 0; reg < 4; ++reg) {
                int row = m0 + rowl + reg;
                float z = acc[ms][ns][reg] + sb[rowl + reg];
                float p = 1.0f / (1.0f + __expf(-z));
                fvout[(size_t)row * 256 + b] = f2bf(p);
            }
        }
    }
}

// ---------------------------------------------------------------------------
// Kernel 2: split-K x split-C GEMM, ZERO LDS, register-only pipeline.
// grid (KG, 2): kg = K-group (16 its), cg = c-half (56 classes, 4 nt tiles).
// B-frags: direct global_load_dwordx4 from outW fp32 into a register double
// buffer (distance 1 it); per-lane (q,l15) -> 16 rows x 128 B per instr.
// 4-wave redundancy served by L1 (14-KB/it working set), waves paced by a
// BARE s_barrier (no waitcnt: all shared state is in registers).
// A-frags: built from shfl'd probabilities (verified mapping, R5/R6).
// Compiler emits per-register s_waitcnt vmcnt(N) on consume - never vmcnt(0).
// ---------------------------------------------------------------------------
__global__ __launch_bounds__(256, 2) void main_gemm(
    const unsigned short* __restrict__ fv, const float* __restrict__ outW,
    _Float16* __restrict__ part16)
{
    const int tid = threadIdx.x;
    const int kg = blockIdx.x;
    const int cg = blockIdx.y;
    const int w = tid >> 6, lane = tid & 63;
    const int q = lane >> 4, l15 = lane & 15;
    const int qh = q >> 1, ql = q & 1;
    const int cmax = cg ? 43 : 55;

    f32x4 zero4 = {0.f, 0.f, 0.f, 0.f};
    f32x4 acc[4][4];
    #pragma unroll
    for (int i = 0; i < 4; ++i)
        #pragma unroll
        for (int j = 0; j < 4; ++j) acc[i][j] = zero4;

    // per-lane B row bases (one per nt), clamped; k-offset = q*8 within 64
    const float* rowp[4];
    #pragma unroll
    for (int nt = 0; nt < 4; ++nt) {
        int r = nt * 16 + l15;
        int rc = r > cmax ? cmax : r;
        rowp[nt] = outW + (size_t)(cg * 56 + rc) * 524288 + q * 8;
    }

    const unsigned short* fvp = fv + tid;

    float4 bbuf[2][16];        // [buf][ch*8 + nt*2 + half]
    unsigned short pvb[2][6];

    // issue B + fv loads for tile `itt` into buffer nb
    #define ISSUE(itt, nb)                                                      \
    {                                                                           \
        const size_t kbase = (size_t)(itt) * 64;                                \
        _Pragma("unroll")                                                       \
        for (int ch = 0; ch < 2; ++ch)                                          \
            _Pragma("unroll")                                                   \
            for (int nt = 0; nt < 4; ++nt) {                                    \
                _Pragma("unroll")                                               \
                for (int half = 0; half < 2; ++half)                            \
                    bbuf[nb][ch * 8 + nt * 2 + half] =                          \
                        *(const float4*)(rowp[nt] + kbase + ch * 32 + half * 4);\
            }                                                                   \
        _Pragma("unroll")                                                       \
        for (int d = 0; d < 6; ++d)                                             \
            pvb[nb][d] = fvp[((size_t)(itt) * 6 + d) * 256];                    \
    }

    ISSUE(kg * ITPB, 0);

    #pragma unroll 2
    for (int itl = 0; itl < ITPB; ++itl) {
        const int cur = itl & 1;

        // prefetch next tile into the other buffer (last iter: reload same)
        const int itn = kg * ITPB + (itl + 1 < ITPB ? itl + 1 : itl);
        ISSUE(itn, cur ^ 1);

        // ---- A-frags from this wave's 64 probability lanes ----
        float p0 = bf2f(pvb[cur][0]), p1 = bf2f(pvb[cur][1]);
        float p2 = bf2f(pvb[cur][2]), p3 = bf2f(pvb[cur][3]);
        float p4 = bf2f(pvb[cur][4]), p5 = bf2f(pvb[cur][5]);

        bf16x8 afr[4][2];
        #pragma unroll
        for (int ms = 0; ms < 4; ++ms) {
            const int src = ms * 16 + l15;
            float s0 = __shfl(p0, src, 64);
            float s1 = __shfl(p1, src, 64);
            float s2 = __shfl(p2, src, 64);
            float s3 = __shfl(p3, src, 64);
            float s4 = __shfl(p4, src, 64);
            float s5 = __shfl(p5, src, 64);
            float t1 = qh ? (1.f - s1) : s1;
            float A0 = s0 * t1;
            float A1 = (1.f - s0) * t1;
            float t2 = ql ? (1.f - s2) : s2;
            float Bv0 = t2 * s3;
            float Bv1 = t2 * (1.f - s3);
            float n4 = 1.f - s4, n5 = 1.f - s5;
            float Cv0 = s4 * s5, Cv1 = s4 * n5, Cv2 = n4 * s5, Cv3 = n4 * n5;
            #pragma unroll
            for (int chl = 0; chl < 2; ++chl) {
                float A = chl ? A1 : A0;
                float ab0 = A * Bv0, ab1 = A * Bv1;
                union { bf16x8 v; unsigned u[4]; } bu;
                bu.u[0] = pk2(ab0 * Cv0, ab0 * Cv1);
                bu.u[1] = pk2(ab0 * Cv2, ab0 * Cv3);
                bu.u[2] = pk2(ab1 * Cv0, ab1 * Cv1);
                bu.u[3] = pk2(ab1 * Cv2, ab1 * Cv3);
                afr[ms][chl] = bu.v;
            }
        }

        // ---- convert B at consume + MFMA (compiler waits per-register) ----
        #pragma unroll
        for (int ch = 0; ch < 2; ++ch) {
            #pragma unroll
            for (int nt = 0; nt < 4; ++nt) {
                float4 b0 = bbuf[cur][ch * 8 + nt * 2 + 0];
                float4 b1 = bbuf[cur][ch * 8 + nt * 2 + 1];
                union { bf16x8 v; unsigned u[4]; } bu;
                bu.u[0] = pk2(b0.x, b0.y);
                bu.u[1] = pk2(b0.z, b0.w);
                bu.u[2] = pk2(b1.x, b1.y);
                bu.u[3] = pk2(b1.z, b1.w);
                #pragma unroll
                for (int ms = 0; ms < 4; ++ms)
                    acc[ms][nt] = __builtin_amdgcn_mfma_f32_16x16x32_bf16(
                        afr[ms][ch], bu.v, acc[ms][nt], 0, 0, 0);
            }
        }

        // pacing only: keep the 4 waves' L1 windows aligned. No waitcnt.
        asm volatile("s_barrier" ::: "memory");
    }
    #undef ISSUE

    // epilogue: part16[b][kg][c], only real c columns for this cg
    const int slotmax = cg ? 44 : 56;
    #pragma unroll
    for (int ms = 0; ms < 4; ++ms) {
        const int brow = w * 64 + ms * 16 + q * 4;
        #pragma unroll
        for (int nt = 0; nt < 4; ++nt) {
            const int slot = nt * 16 + l15;
            if (slot < slotmax) {
                const int c = cg * 56 + slot;
                #pragma unroll
                for (int reg = 0; reg < 4; ++reg)
                    part16[((size_t)(brow + reg) * KG + kg) * 112 + c] =
                        (_Float16)acc[ms][nt][reg];
            }
        }
    }
}

// ---------------------------------------------------------------------------
// Kernel 3: out[b][c] = sum_kg part16[b][kg][c] + out_b[c]
// One block per b; slice = 512*112 halves = 114688 B contiguous.
// ---------------------------------------------------------------------------
__global__ __launch_bounds__(256) void reduce_k(
    const _Float16* __restrict__ part16, const float* __restrict__ outb,
    float* __restrict__ out)
{
    __shared__ float red[16 * 112];
    const int b = blockIdx.x;
    const int tid = threadIdx.x;
    const f16x8* slice = (const f16x8*)(part16 + (size_t)b * (KG * 112));

    if (tid < 224) {
        const int c8 = tid % 14;       // c base = c8*8
        const int kgs = tid / 14;      // 0..15
        float s[8];
        #pragma unroll
        for (int j = 0; j < 8; ++j) s[j] = 0.f;
        #pragma unroll 4
        for (int i = 0; i < 32; ++i) { // kg = i*16 + kgs
            f16x8 v = slice[i * 224 + tid];
            #pragma unroll
            for (int j = 0; j < 8; ++j) s[j] += (float)v[j];
        }
        #pragma unroll
        for (int j = 0; j < 8; ++j) red[kgs * 112 + c8 * 8 + j] = s[j];
    }
    __syncthreads();
    if (tid < CC) {
        float r = outb[tid];
        #pragma unroll
        for (int k = 0; k < 16; ++k) r += red[k * 112 + tid];
        out[b * CC + tid] = r;
    }
}

extern "C" void kernel_launch(void* const* d_in, const int* in_sizes, int n_in,
                              void* d_out, int out_size, void* d_ws, size_t ws_size,
                              hipStream_t stream) {
    const float* x    = (const float*)d_in[0];
    const float* selW = (const float*)d_in[1];
    const float* selb = (const float*)d_in[2];
    const float* outW = (const float*)d_in[3];
    const float* outb = (const float*)d_in[4];
    float* out = (float*)d_out;

    // ws: fv bf16 [49152*256]          = 25,165,824 B
    //     part16  [256][512][112] fp16 = 29,360,128 B   (offset 25,165,824)
    unsigned short* fv = (unsigned short*)d_ws;
    _Float16* part16 = (_Float16*)((char*)d_ws + 25165824);

    fv_kernel<<<dim3(384, 2), 256, 0, stream>>>(x, selW, selb, fv);
    main_gemm<<<dim3(KG, 2), 256, 0, stream>>>(fv, outW, part16);
    reduce_k<<<BB, 256, 0, stream>>>(part16, outb, out);
}